// Round 1
// baseline (1005.305 us; speedup 1.0000x reference)
//
#include <hip/hip_runtime.h>
#include <hip/hip_bf16.h>

// Problem constants (fixed by setup_inputs): B=8192, N=M=2048, H=10.
// Pipeline:
//   1) col/row sums of weight (partials -> finish, deterministic, no atomics)
//   2) per-cell MLP -> new_weight (fp32, in d_ws)
//   3) fp32 SGEMM  logits = X @ new_weight  -> d_out
//   4) row softmax in-place on d_out

#define BM 128
#define BN 128
#define BK 16

// ---------------- col sums (partials over 8 row-chunks, then reduce) --------
__global__ __launch_bounds__(256) void colsum_part_kernel(
    const float* __restrict__ W, float* __restrict__ part, int N, int M) {
  int j = blockIdx.x * 256 + threadIdx.x;     // column
  int chunk = blockIdx.y;                     // row chunk
  int rows_per_chunk = N / gridDim.y;
  int i0 = chunk * rows_per_chunk;
  float s = 0.f;
  for (int i = i0; i < i0 + rows_per_chunk; ++i)
    s += W[(size_t)i * M + j];
  part[(size_t)chunk * M + j] = s;
}

__global__ __launch_bounds__(256) void colsum_finish_kernel(
    const float* __restrict__ part, float* __restrict__ colS, int M, int nchunk) {
  int j = blockIdx.x * 256 + threadIdx.x;
  float s = 0.f;
  for (int c = 0; c < nchunk; ++c) s += part[(size_t)c * M + j];
  colS[j] = s;
}

// ---------------- row sums (one block per row) ------------------------------
__global__ __launch_bounds__(256) void rowsum_kernel(
    const float* __restrict__ W, float* __restrict__ rowS, int M) {
  int row = blockIdx.x;
  int tid = threadIdx.x;
  const float4* p = (const float4*)(W + (size_t)row * M);
  float4 a = p[tid];
  float4 b = p[tid + 256];
  float v = (a.x + a.y) + (a.z + a.w) + (b.x + b.y) + (b.z + b.w);
  __shared__ float red[256];
  red[tid] = v;
  __syncthreads();
  for (int s = 128; s > 0; s >>= 1) {
    if (tid < s) red[tid] += red[tid + s];
    __syncthreads();
  }
  if (tid == 0) rowS[row] = red[0];
}

// ---------------- per-cell NCA MLP -> new_weight ----------------------------
__global__ __launch_bounds__(256) void nca_update_kernel(
    const float* __restrict__ W, const float* __restrict__ colS,
    const float* __restrict__ rowS,
    const float* __restrict__ W1, const float* __restrict__ b1,
    const float* __restrict__ W2, const float* __restrict__ b2,
    const float* __restrict__ W3, const float* __restrict__ b3,
    float* __restrict__ Wn, int N, int M) {
  __shared__ float sW1[30], sb1[10], sW2[100], sb2[10], sW3[10], sb3;
  int tid = threadIdx.x;
  if (tid < 30) sW1[tid] = W1[tid];
  if (tid < 10) { sb1[tid] = b1[tid]; sb2[tid] = b2[tid]; sW3[tid] = W3[tid]; }
  if (tid >= 32 && tid < 132) sW2[tid - 32] = W2[tid - 32];
  if (tid == 0) sb3 = b3[0];
  __syncthreads();

  size_t idx = (size_t)blockIdx.x * 256 + tid;
  if (idx >= (size_t)N * M) return;
  int i = (int)(idx / M);
  int j = (int)(idx % M);
  float w = W[idx];
  float fwd = (colS[j] - w) / (float)(N - 1);
  float bwd = (rowS[i] - w) / (float)(M - 1);

  float h1[10];
#pragma unroll
  for (int o = 0; o < 10; ++o) {
    float v = fmaf(w, sW1[o], fmaf(fwd, sW1[10 + o], fmaf(bwd, sW1[20 + o], sb1[o])));
    h1[o] = fmaxf(v, 0.f);
  }
  float u = sb3;
#pragma unroll
  for (int o = 0; o < 10; ++o) {
    float h2 = sb2[o];
#pragma unroll
    for (int p = 0; p < 10; ++p) h2 = fmaf(h1[p], sW2[p * 10 + o], h2);
    u = fmaf(fmaxf(h2, 0.f), sW3[o], u);
  }
  Wn[idx] = w + u;
}

// ---------------- fp32 SGEMM: C[Bdim,M] = A[Bdim,K] * Wn[K,M] ---------------
// 128x128 block tile, 256 threads, 8x8 micro-tile (split 8x4 + 8x4 at +64
// columns so LDS B-reads are at worst 2-way bank-aliased, which is free).
__global__ __launch_bounds__(256) void sgemm_kernel(
    const float* __restrict__ A, const float* __restrict__ Bmat,
    float* __restrict__ C, int K, int M) {
  __shared__ float As[BK][BM + 4];
  __shared__ float Bs[BK][BN + 4];

  const int tid = threadIdx.x;
  const int tm = tid >> 4;   // 0..15 -> row group (8 rows)
  const int tn = tid & 15;   // 0..15 -> col group (4 + 4 cols)
  const int bx = blockIdx.x; // N tile
  const int by = blockIdx.y; // M (batch-row) tile

  const float* Aptr = A + (size_t)(by * BM) * K;
  const float* Bptr = Bmat + (size_t)bx * BN;

  float acc[8][8];
#pragma unroll
  for (int i = 0; i < 8; ++i)
#pragma unroll
    for (int j = 0; j < 8; ++j) acc[i][j] = 0.f;

  for (int k0 = 0; k0 < K; k0 += BK) {
    // Stage A tile: 128x16, 512 float4 loads, 2 per thread (transpose to As[k][m])
#pragma unroll
    for (int r = 0; r < 2; ++r) {
      int l = tid + 256 * r;
      int row = l >> 2;             // 0..127
      int kc  = (l & 3) * 4;        // 0,4,8,12
      float4 v = *(const float4*)(Aptr + (size_t)row * K + k0 + kc);
      As[kc + 0][row] = v.x;
      As[kc + 1][row] = v.y;
      As[kc + 2][row] = v.z;
      As[kc + 3][row] = v.w;
    }
    // Stage B tile: 16x128, fully coalesced float4, stored as-is
#pragma unroll
    for (int r = 0; r < 2; ++r) {
      int l = tid + 256 * r;
      int row = l >> 5;             // 0..15
      int nc  = (l & 31) * 4;       // 0..124
      float4 v = *(const float4*)(Bptr + (size_t)(k0 + row) * M + nc);
      *(float4*)&Bs[row][nc] = v;
    }
    __syncthreads();

#pragma unroll
    for (int k = 0; k < BK; ++k) {
      float4 a0 = *(const float4*)&As[k][tm * 8];
      float4 a1 = *(const float4*)&As[k][tm * 8 + 4];
      float4 b0 = *(const float4*)&Bs[k][tn * 4];
      float4 b1 = *(const float4*)&Bs[k][tn * 4 + 64];
      float a[8] = {a0.x, a0.y, a0.z, a0.w, a1.x, a1.y, a1.z, a1.w};
      float b[8] = {b0.x, b0.y, b0.z, b0.w, b1.x, b1.y, b1.z, b1.w};
#pragma unroll
      for (int i = 0; i < 8; ++i)
#pragma unroll
        for (int j = 0; j < 8; ++j)
          acc[i][j] = fmaf(a[i], b[j], acc[i][j]);
    }
    __syncthreads();
  }

  // Epilogue: two float4 stores per micro-row (cols tn*4 and tn*4+64)
  const int col0 = bx * BN + tn * 4;
#pragma unroll
  for (int i = 0; i < 8; ++i) {
    size_t rbase = (size_t)(by * BM + tm * 8 + i) * M;
    *(float4*)(C + rbase + col0)      = make_float4(acc[i][0], acc[i][1], acc[i][2], acc[i][3]);
    *(float4*)(C + rbase + col0 + 64) = make_float4(acc[i][4], acc[i][5], acc[i][6], acc[i][7]);
  }
}

// ---------------- row softmax in place --------------------------------------
__global__ __launch_bounds__(256) void softmax_kernel(float* __restrict__ C, int M) {
  int row = blockIdx.x;
  int tid = threadIdx.x;
  float4* p = (float4*)(C + (size_t)row * M);
  float4 a = p[tid];
  float4 b = p[tid + 256];

  float vmax = fmaxf(fmaxf(fmaxf(a.x, a.y), fmaxf(a.z, a.w)),
                     fmaxf(fmaxf(b.x, b.y), fmaxf(b.z, b.w)));
  __shared__ float red[256];
  red[tid] = vmax;
  __syncthreads();
  for (int s = 128; s > 0; s >>= 1) {
    if (tid < s) red[tid] = fmaxf(red[tid], red[tid + s]);
    __syncthreads();
  }
  float m = red[0];
  __syncthreads();

  float e[8];
  e[0] = expf(a.x - m); e[1] = expf(a.y - m); e[2] = expf(a.z - m); e[3] = expf(a.w - m);
  e[4] = expf(b.x - m); e[5] = expf(b.y - m); e[6] = expf(b.z - m); e[7] = expf(b.w - m);
  float sum = ((e[0] + e[1]) + (e[2] + e[3])) + ((e[4] + e[5]) + (e[6] + e[7]));

  red[tid] = sum;
  __syncthreads();
  for (int s = 128; s > 0; s >>= 1) {
    if (tid < s) red[tid] += red[tid + s];
    __syncthreads();
  }
  float inv = 1.0f / red[0];

  a = make_float4(e[0] * inv, e[1] * inv, e[2] * inv, e[3] * inv);
  b = make_float4(e[4] * inv, e[5] * inv, e[6] * inv, e[7] * inv);
  p[tid] = a;
  p[tid + 256] = b;
}

// ---------------- launcher --------------------------------------------------
extern "C" void kernel_launch(void* const* d_in, const int* in_sizes, int n_in,
                              void* d_out, int out_size, void* d_ws, size_t ws_size,
                              hipStream_t stream) {
  const float* X      = (const float*)d_in[0];
  const float* weight = (const float*)d_in[1];
  const float* W1     = (const float*)d_in[2];
  const float* b1     = (const float*)d_in[3];
  const float* W2     = (const float*)d_in[4];
  const float* b2     = (const float*)d_in[5];
  const float* W3     = (const float*)d_in[6];
  const float* b3     = (const float*)d_in[7];
  float* out = (float*)d_out;

  const int N = 2048, M = 2048;
  const int Bdim = in_sizes[0] / N;   // 8192

  // workspace layout (floats): colS[M] | rowS[N] | part[8*M] | Wn[N*M]
  float* colS = (float*)d_ws;
  float* rowS = colS + M;
  float* part = rowS + N;
  float* Wn   = part + 8 * M;

  const int NCHUNK = 8;
  colsum_part_kernel<<<dim3(M / 256, NCHUNK), 256, 0, stream>>>(weight, part, N, M);
  colsum_finish_kernel<<<M / 256, 256, 0, stream>>>(part, colS, M, NCHUNK);
  rowsum_kernel<<<N, 256, 0, stream>>>(weight, rowS, M);

  nca_update_kernel<<<(N * M) / 256, 256, 0, stream>>>(
      weight, colS, rowS, W1, b1, W2, b2, W3, b3, Wn, N, M);

  sgemm_kernel<<<dim3(M / BN, Bdim / BM), 256, 0, stream>>>(X, Wn, out, N, M);

  softmax_kernel<<<Bdim, 256, 0, stream>>>(out, M);
}

// Round 2
// 529.508 us; speedup vs baseline: 1.8986x; 1.8986x over previous
//
#include <hip/hip_runtime.h>
#include <hip/hip_bf16.h>

// B=8192, N=M=K=2048, H=10.
// Pipeline:
//   1) convert X -> Xh, Xl (bf16 split, row-major)
//   2) col/row sums of weight
//   3) NCA MLP -> new_weight, written as TRANSPOSED bf16 split Bth/Btl [M][N]
//   4) 3-term bf16 MFMA GEMM: logits = Xh*Bh + Xl*Bh + Xh*Bl -> d_out (fp32)
//   5) row softmax in place

typedef short short8 __attribute__((ext_vector_type(8)));
typedef float floatx4 __attribute__((ext_vector_type(4)));

__device__ inline unsigned short f2bf_rne(float x) {
  unsigned u = __float_as_uint(x);
  unsigned r = (u + 0x7fffu + ((u >> 16) & 1u)) >> 16;
  return (unsigned short)r;
}
__device__ inline float bf2f(unsigned short h) {
  return __uint_as_float(((unsigned)h) << 16);
}

// ---------------- X -> bf16 split -------------------------------------------
__global__ __launch_bounds__(256) void convx_kernel(
    const float* __restrict__ X, unsigned short* __restrict__ Xh,
    unsigned short* __restrict__ Xl) {
  size_t i = (size_t)blockIdx.x * 256 + threadIdx.x;  // float4 index
  float4 v = ((const float4*)X)[i];
  ushort4 h, l;
  h.x = f2bf_rne(v.x); l.x = f2bf_rne(v.x - bf2f(h.x));
  h.y = f2bf_rne(v.y); l.y = f2bf_rne(v.y - bf2f(h.y));
  h.z = f2bf_rne(v.z); l.z = f2bf_rne(v.z - bf2f(h.z));
  h.w = f2bf_rne(v.w); l.w = f2bf_rne(v.w - bf2f(h.w));
  ((ushort4*)Xh)[i] = h;
  ((ushort4*)Xl)[i] = l;
}

// ---------------- col sums (partials over 8 row-chunks, then reduce) --------
__global__ __launch_bounds__(256) void colsum_part_kernel(
    const float* __restrict__ W, float* __restrict__ part, int N, int M) {
  int j = blockIdx.x * 256 + threadIdx.x;
  int chunk = blockIdx.y;
  int rows_per_chunk = N / gridDim.y;
  int i0 = chunk * rows_per_chunk;
  float s = 0.f;
  for (int i = i0; i < i0 + rows_per_chunk; ++i) s += W[(size_t)i * M + j];
  part[(size_t)chunk * M + j] = s;
}

__global__ __launch_bounds__(256) void colsum_finish_kernel(
    const float* __restrict__ part, float* __restrict__ colS, int M, int nchunk) {
  int j = blockIdx.x * 256 + threadIdx.x;
  float s = 0.f;
  for (int c = 0; c < nchunk; ++c) s += part[(size_t)c * M + j];
  colS[j] = s;
}

__global__ __launch_bounds__(256) void rowsum_kernel(
    const float* __restrict__ W, float* __restrict__ rowS, int M) {
  int row = blockIdx.x;
  int tid = threadIdx.x;
  const float4* p = (const float4*)(W + (size_t)row * M);
  float4 a = p[tid];
  float4 b = p[tid + 256];
  float v = (a.x + a.y) + (a.z + a.w) + (b.x + b.y) + (b.z + b.w);
  __shared__ float red[256];
  red[tid] = v;
  __syncthreads();
  for (int s = 128; s > 0; s >>= 1) {
    if (tid < s) red[tid] += red[tid + s];
    __syncthreads();
  }
  if (tid == 0) rowS[row] = red[0];
}

// ------- NCA MLP -> new_weight, transposed bf16 split out -------------------
// One block per 32x32 tile of weight; writes Bth/Btl[j][i] (i.e. [M][N]).
__global__ __launch_bounds__(256) void nca_update_kernel(
    const float* __restrict__ W, const float* __restrict__ colS,
    const float* __restrict__ rowS,
    const float* __restrict__ W1, const float* __restrict__ b1,
    const float* __restrict__ W2, const float* __restrict__ b2,
    const float* __restrict__ W3, const float* __restrict__ b3,
    unsigned short* __restrict__ Bth, unsigned short* __restrict__ Btl,
    int N, int M) {
  __shared__ float sW1[30], sb1[10], sW2[100], sb2[10], sW3[10], sb3;
  __shared__ unsigned short Th[32][33], Tl[32][33];
  int tid = threadIdx.x;
  if (tid < 30) sW1[tid] = W1[tid];
  if (tid < 10) { sb1[tid] = b1[tid]; sb2[tid] = b2[tid]; sW3[tid] = W3[tid]; }
  if (tid >= 32 && tid < 132) sW2[tid - 32] = W2[tid - 32];
  if (tid == 0) sb3 = b3[0];
  __syncthreads();

  int i0 = blockIdx.y * 32;
  int j0 = blockIdx.x * 32;
  int r = tid >> 5;   // 0..7
  int c = tid & 31;   // 0..31

#pragma unroll
  for (int rr = 0; rr < 4; ++rr) {
    int il = r + 8 * rr;
    size_t idx = (size_t)(i0 + il) * M + j0 + c;
    float w = W[idx];
    float fwd = (colS[j0 + c] - w) / (float)(N - 1);
    float bwd = (rowS[i0 + il] - w) / (float)(M - 1);
    float h1[10];
#pragma unroll
    for (int o = 0; o < 10; ++o) {
      float v = fmaf(w, sW1[o], fmaf(fwd, sW1[10 + o], fmaf(bwd, sW1[20 + o], sb1[o])));
      h1[o] = fmaxf(v, 0.f);
    }
    float u = sb3;
#pragma unroll
    for (int o = 0; o < 10; ++o) {
      float h2 = sb2[o];
#pragma unroll
      for (int p = 0; p < 10; ++p) h2 = fmaf(h1[p], sW2[p * 10 + o], h2);
      u = fmaf(fmaxf(h2, 0.f), sW3[o], u);
    }
    float nw = w + u;
    unsigned short hb = f2bf_rne(nw);
    Th[il][c] = hb;
    Tl[il][c] = f2bf_rne(nw - bf2f(hb));
  }
  __syncthreads();

  // transposed write: out[j][i] = T[i_local=c][j_local]
#pragma unroll
  for (int rr = 0; rr < 4; ++rr) {
    int jl = r + 8 * rr;
    size_t oidx = (size_t)(j0 + jl) * N + i0 + c;
    Bth[oidx] = Th[c][jl];
    Btl[oidx] = Tl[c][jl];
  }
}

// ---------------- 3-term bf16 MFMA GEMM -------------------------------------
// C[8192,2048] = X[8192,2048(K)] * Wn[K,2048];  Bt arrays are Wn^T: [n][k].
// Block: 256 threads (4 waves), 128x128 tile, BK=32, single-buffered LDS,
// global_load_lds width=16 staging (m97 structure).
#define GK 2048
__global__ __launch_bounds__(256) void gemm_kernel(
    const unsigned short* __restrict__ Xh, const unsigned short* __restrict__ Xl,
    const unsigned short* __restrict__ Bth, const unsigned short* __restrict__ Btl,
    float* __restrict__ C) {
  __shared__ short sAh[128 * 32];
  __shared__ short sAl[128 * 32];
  __shared__ short sBh[128 * 32];
  __shared__ short sBl[128 * 32];

  const int tid = threadIdx.x;
  const int lane = tid & 63;
  const int wave = tid >> 6;
  const int wr = wave >> 1;    // 0..1 : 64-row quadrant
  const int wc = wave & 1;     // 0..1 : 64-col quadrant
  const int fm = lane & 15;
  const int q = lane >> 4;

  const int bx = blockIdx.x;   // col tile (0..15)
  const int by = blockIdx.y;   // row tile (0..63)

  const unsigned short* A0h = Xh + (size_t)(by * 128) * GK;
  const unsigned short* A0l = Xl + (size_t)(by * 128) * GK;
  const unsigned short* B0h = Bth + (size_t)(bx * 128) * GK;
  const unsigned short* B0l = Btl + (size_t)(bx * 128) * GK;

  const int rowBase = 32 * wave;          // this wave stages rows [32w, 32w+32)
  const int srow = lane >> 2;             // 0..15 row within 16-row chunk
  const int skof = (lane & 3) * 8;        // k offset 0/8/16/24

  floatx4 acc[4][4];
#pragma unroll
  for (int i = 0; i < 4; ++i)
#pragma unroll
    for (int j = 0; j < 4; ++j) acc[i][j] = (floatx4){0.f, 0.f, 0.f, 0.f};

  for (int k0 = 0; k0 < GK; k0 += 32) {
#pragma unroll
    for (int r = 0; r < 2; ++r) {
      int row = rowBase + 16 * r + srow;
      int ldsoff = (rowBase + 16 * r) * 32;
      __builtin_amdgcn_global_load_lds(
          (const __attribute__((address_space(1))) void*)(A0h + (size_t)row * GK + k0 + skof),
          (__attribute__((address_space(3))) void*)(sAh + ldsoff), 16, 0, 0);
      __builtin_amdgcn_global_load_lds(
          (const __attribute__((address_space(1))) void*)(A0l + (size_t)row * GK + k0 + skof),
          (__attribute__((address_space(3))) void*)(sAl + ldsoff), 16, 0, 0);
      __builtin_amdgcn_global_load_lds(
          (const __attribute__((address_space(1))) void*)(B0h + (size_t)row * GK + k0 + skof),
          (__attribute__((address_space(3))) void*)(sBh + ldsoff), 16, 0, 0);
      __builtin_amdgcn_global_load_lds(
          (const __attribute__((address_space(1))) void*)(B0l + (size_t)row * GK + k0 + skof),
          (__attribute__((address_space(3))) void*)(sBl + ldsoff), 16, 0, 0);
    }
    __syncthreads();

    short8 ah[4], al[4], bh[4], bl[4];
#pragma unroll
    for (int mi = 0; mi < 4; ++mi) {
      int off = (wr * 64 + mi * 16 + fm) * 32 + q * 8;
      ah[mi] = *(const short8*)(sAh + off);
      al[mi] = *(const short8*)(sAl + off);
    }
#pragma unroll
    for (int ni = 0; ni < 4; ++ni) {
      int off = (wc * 64 + ni * 16 + fm) * 32 + q * 8;
      bh[ni] = *(const short8*)(sBh + off);
      bl[ni] = *(const short8*)(sBl + off);
    }
#pragma unroll
    for (int mi = 0; mi < 4; ++mi)
#pragma unroll
      for (int ni = 0; ni < 4; ++ni) {
        acc[mi][ni] = __builtin_amdgcn_mfma_f32_16x16x32_bf16(ah[mi], bh[ni], acc[mi][ni], 0, 0, 0);
        acc[mi][ni] = __builtin_amdgcn_mfma_f32_16x16x32_bf16(al[mi], bh[ni], acc[mi][ni], 0, 0, 0);
        acc[mi][ni] = __builtin_amdgcn_mfma_f32_16x16x32_bf16(ah[mi], bl[ni], acc[mi][ni], 0, 0, 0);
      }
    __syncthreads();
  }

  // epilogue: C/D layout col=lane&15, row=quad*4+reg
#pragma unroll
  for (int mi = 0; mi < 4; ++mi)
#pragma unroll
    for (int ni = 0; ni < 4; ++ni) {
      int col = bx * 128 + wc * 64 + ni * 16 + fm;
#pragma unroll
      for (int r = 0; r < 4; ++r) {
        int row = by * 128 + wr * 64 + mi * 16 + q * 4 + r;
        C[(size_t)row * 2048 + col] = acc[mi][ni][r];
      }
    }
}

// ---------------- row softmax in place --------------------------------------
__global__ __launch_bounds__(256) void softmax_kernel(float* __restrict__ C, int M) {
  int row = blockIdx.x;
  int tid = threadIdx.x;
  float4* p = (float4*)(C + (size_t)row * M);
  float4 a = p[tid];
  float4 b = p[tid + 256];

  float vmax = fmaxf(fmaxf(fmaxf(a.x, a.y), fmaxf(a.z, a.w)),
                     fmaxf(fmaxf(b.x, b.y), fmaxf(b.z, b.w)));
  __shared__ float red[256];
  red[tid] = vmax;
  __syncthreads();
  for (int s = 128; s > 0; s >>= 1) {
    if (tid < s) red[tid] = fmaxf(red[tid], red[tid + s]);
    __syncthreads();
  }
  float m = red[0];
  __syncthreads();

  float e[8];
  e[0] = expf(a.x - m); e[1] = expf(a.y - m); e[2] = expf(a.z - m); e[3] = expf(a.w - m);
  e[4] = expf(b.x - m); e[5] = expf(b.y - m); e[6] = expf(b.z - m); e[7] = expf(b.w - m);
  float sum = ((e[0] + e[1]) + (e[2] + e[3])) + ((e[4] + e[5]) + (e[6] + e[7]));

  red[tid] = sum;
  __syncthreads();
  for (int s = 128; s > 0; s >>= 1) {
    if (tid < s) red[tid] += red[tid + s];
    __syncthreads();
  }
  float inv = 1.0f / red[0];

  a = make_float4(e[0] * inv, e[1] * inv, e[2] * inv, e[3] * inv);
  b = make_float4(e[4] * inv, e[5] * inv, e[6] * inv, e[7] * inv);
  p[tid] = a;
  p[tid + 256] = b;
}

// ---------------- launcher --------------------------------------------------
extern "C" void kernel_launch(void* const* d_in, const int* in_sizes, int n_in,
                              void* d_out, int out_size, void* d_ws, size_t ws_size,
                              hipStream_t stream) {
  const float* X      = (const float*)d_in[0];
  const float* weight = (const float*)d_in[1];
  const float* W1     = (const float*)d_in[2];
  const float* b1     = (const float*)d_in[3];
  const float* W2     = (const float*)d_in[4];
  const float* b2     = (const float*)d_in[5];
  const float* W3     = (const float*)d_in[6];
  const float* b3     = (const float*)d_in[7];
  float* out = (float*)d_out;

  const int N = 2048, M = 2048;
  const int Bdim = in_sizes[0] / N;   // 8192

  // workspace: colS[2048] rowS[2048] part[8*2048] (fp32) | Xh Xl [B*N] | Bth Btl [M*N] (ushort)
  float* colS = (float*)d_ws;
  float* rowS = colS + 2048;
  float* part = rowS + 2048;
  unsigned short* Xh  = (unsigned short*)(part + 8 * 2048);
  unsigned short* Xl  = Xh + (size_t)Bdim * N;
  unsigned short* Bth = Xl + (size_t)Bdim * N;
  unsigned short* Btl = Bth + (size_t)M * N;

  convx_kernel<<<(Bdim * N) / 4 / 256, 256, 0, stream>>>(X, Xh, Xl);

  colsum_part_kernel<<<dim3(M / 256, 8), 256, 0, stream>>>(weight, part, N, M);
  colsum_finish_kernel<<<M / 256, 256, 0, stream>>>(part, colS, M, 8);
  rowsum_kernel<<<N, 256, 0, stream>>>(weight, rowS, M);

  nca_update_kernel<<<dim3(M / 32, N / 32), 256, 0, stream>>>(
      weight, colS, rowS, W1, b1, W2, b2, W3, b3, Bth, Btl, N, M);

  gemm_kernel<<<dim3(M / 128, Bdim / 128), 256, 0, stream>>>(Xh, Xl, Bth, Btl, out);

  softmax_kernel<<<Bdim, 256, 0, stream>>>(out, M);
}

// Round 3
// 435.321 us; speedup vs baseline: 2.3093x; 1.2164x over previous
//
#include <hip/hip_runtime.h>
#include <hip/hip_bf16.h>

// B=8192, N=M=K=2048, H=10.
// Pipeline (4 launches):
//   1) pre_kernel: fused [X -> Xh,Xl bf16 split] + [row sums] + [col-sum partials]
//   2) nca_update: finish col sums inline, per-cell MLP, write TRANSPOSED bf16
//      split Bth/Btl [M][N]
//   3) 3-term bf16 MFMA GEMM: logits = Xh*Bh + Xl*Bh + Xh*Bl -> d_out (fp32)
//   4) row softmax in place (wave-shuffle reductions)

typedef short short8 __attribute__((ext_vector_type(8)));
typedef float floatx4 __attribute__((ext_vector_type(4)));

#define GK 2048
#define NROWS 2048
#define MCOLS 2048

__device__ inline unsigned short f2bf_rne(float x) {
  unsigned u = __float_as_uint(x);
  unsigned r = (u + 0x7fffu + ((u >> 16) & 1u)) >> 16;
  return (unsigned short)r;
}
__device__ inline float bf2f(unsigned short h) {
  return __uint_as_float(((unsigned)h) << 16);
}

// ---------------- fused pre-pass --------------------------------------------
// blocks [0, 16384)          : X -> Xh/Xl split (1 float4 per thread)
// blocks [16384, 16384+2048) : row sums of weight (1 row per block)
// blocks [16384+2048, +64)   : col-sum partials (8 chunks x 8 col-blocks)
#define CONV_BLOCKS 16384
__global__ __launch_bounds__(256) void pre_kernel(
    const float* __restrict__ X, const float* __restrict__ W,
    unsigned short* __restrict__ Xh, unsigned short* __restrict__ Xl,
    float* __restrict__ part, float* __restrict__ rowS) {
  const int bid = blockIdx.x;
  const int tid = threadIdx.x;

  if (bid < CONV_BLOCKS) {
    size_t i = (size_t)bid * 256 + tid;
    float4 v = ((const float4*)X)[i];
    ushort4 h, l;
    h.x = f2bf_rne(v.x); l.x = f2bf_rne(v.x - bf2f(h.x));
    h.y = f2bf_rne(v.y); l.y = f2bf_rne(v.y - bf2f(h.y));
    h.z = f2bf_rne(v.z); l.z = f2bf_rne(v.z - bf2f(h.z));
    h.w = f2bf_rne(v.w); l.w = f2bf_rne(v.w - bf2f(h.w));
    ((ushort4*)Xh)[i] = h;
    ((ushort4*)Xl)[i] = l;
  } else if (bid < CONV_BLOCKS + NROWS) {
    int row = bid - CONV_BLOCKS;
    const float4* p = (const float4*)(W + (size_t)row * MCOLS);
    float4 a = p[tid];
    float4 b = p[tid + 256];
    float v = (a.x + a.y) + (a.z + a.w) + (b.x + b.y) + (b.z + b.w);
    __shared__ float red[256];
    red[tid] = v;
    __syncthreads();
    for (int s = 128; s > 0; s >>= 1) {
      if (tid < s) red[tid] += red[tid + s];
      __syncthreads();
    }
    if (tid == 0) rowS[row] = red[0];
  } else {
    int b = bid - CONV_BLOCKS - NROWS;   // 0..63
    int j = (b & 7) * 256 + tid;         // column
    int chunk = b >> 3;                  // 0..7
    int i0 = chunk * (NROWS / 8);
    float s = 0.f;
    for (int i = i0; i < i0 + NROWS / 8; ++i) s += W[(size_t)i * MCOLS + j];
    part[(size_t)chunk * MCOLS + j] = s;
  }
}

// ------- NCA MLP -> new_weight, transposed bf16 split out -------------------
// One block per 32x32 tile of weight; finishes colsum partials inline;
// processes 4 cells per thread SIMULTANEOUSLY so sW2 broadcast reads amortize.
__global__ __launch_bounds__(256) void nca_update_kernel(
    const float* __restrict__ W, const float* __restrict__ part,
    const float* __restrict__ rowS,
    const float* __restrict__ W1, const float* __restrict__ b1,
    const float* __restrict__ W2, const float* __restrict__ b2,
    const float* __restrict__ W3, const float* __restrict__ b3,
    unsigned short* __restrict__ Bth, unsigned short* __restrict__ Btl) {
  __shared__ float sW1[30], sb1[10], sW2[100], sb2[10], sW3[10], sb3;
  __shared__ float sColS[32];
  __shared__ float cred[8][33];
  __shared__ unsigned short Th[32][33], Tl[32][33];
  const int tid = threadIdx.x;
  const int i0 = blockIdx.y * 32;
  const int j0 = blockIdx.x * 32;

  if (tid < 30) sW1[tid] = W1[tid];
  if (tid < 10) { sb1[tid] = b1[tid]; sb2[tid] = b2[tid]; sW3[tid] = W3[tid]; }
  if (tid >= 32 && tid < 132) sW2[tid - 32] = W2[tid - 32];
  if (tid == 0) sb3 = b3[0];

  // finish column sums for this block's 32 columns
  {
    int ch = tid >> 5;       // 0..7
    int jl = tid & 31;
    cred[ch][jl] = part[(size_t)ch * MCOLS + j0 + jl];
  }
  __syncthreads();
  if (tid < 32) {
    float s = 0.f;
#pragma unroll
    for (int c = 0; c < 8; ++c) s += cred[c][tid];
    sColS[tid] = s;
  }
  __syncthreads();

  const int r = tid >> 5;   // 0..7
  const int c = tid & 31;   // 0..31

  float w[4], fwd[4], bwd[4];
#pragma unroll
  for (int cell = 0; cell < 4; ++cell) {
    int il = r + 8 * cell;
    float wv = W[(size_t)(i0 + il) * MCOLS + j0 + c];
    w[cell] = wv;
    fwd[cell] = (sColS[c] - wv) * (1.0f / (float)(NROWS - 1));
    bwd[cell] = (rowS[i0 + il] - wv) * (1.0f / (float)(MCOLS - 1));
  }

  float h1[4][10];
#pragma unroll
  for (int o = 0; o < 10; ++o) {
    float w1a = sW1[o], w1b = sW1[10 + o], w1c = sW1[20 + o], bb = sb1[o];
#pragma unroll
    for (int cell = 0; cell < 4; ++cell) {
      float v = fmaf(w[cell], w1a, fmaf(fwd[cell], w1b, fmaf(bwd[cell], w1c, bb)));
      h1[cell][o] = fmaxf(v, 0.f);
    }
  }
  float u[4] = {sb3, sb3, sb3, sb3};
#pragma unroll
  for (int o = 0; o < 10; ++o) {
    float h2[4];
    float bb = sb2[o];
#pragma unroll
    for (int cell = 0; cell < 4; ++cell) h2[cell] = bb;
#pragma unroll
    for (int p = 0; p < 10; ++p) {
      float wv = sW2[p * 10 + o];
#pragma unroll
      for (int cell = 0; cell < 4; ++cell) h2[cell] = fmaf(h1[cell][p], wv, h2[cell]);
    }
    float w3 = sW3[o];
#pragma unroll
    for (int cell = 0; cell < 4; ++cell) u[cell] = fmaf(fmaxf(h2[cell], 0.f), w3, u[cell]);
  }

#pragma unroll
  for (int cell = 0; cell < 4; ++cell) {
    int il = r + 8 * cell;
    float nw = w[cell] + u[cell];
    unsigned short hb = f2bf_rne(nw);
    Th[il][c] = hb;
    Tl[il][c] = f2bf_rne(nw - bf2f(hb));
  }
  __syncthreads();

  // transposed write: out[j][i] = T[i_local=c][j_local]
#pragma unroll
  for (int cell = 0; cell < 4; ++cell) {
    int jl = r + 8 * cell;
    size_t oidx = (size_t)(j0 + jl) * NROWS + i0 + c;
    Bth[oidx] = Th[c][jl];
    Btl[oidx] = Tl[c][jl];
  }
}

// ---------------- 3-term bf16 MFMA GEMM (unchanged, m97 structure) ----------
__global__ __launch_bounds__(256) void gemm_kernel(
    const unsigned short* __restrict__ Xh, const unsigned short* __restrict__ Xl,
    const unsigned short* __restrict__ Bth, const unsigned short* __restrict__ Btl,
    float* __restrict__ C) {
  __shared__ short sAh[128 * 32];
  __shared__ short sAl[128 * 32];
  __shared__ short sBh[128 * 32];
  __shared__ short sBl[128 * 32];

  const int tid = threadIdx.x;
  const int lane = tid & 63;
  const int wave = tid >> 6;
  const int wr = wave >> 1;
  const int wc = wave & 1;
  const int fm = lane & 15;
  const int q = lane >> 4;

  const int bx = blockIdx.x;
  const int by = blockIdx.y;

  const unsigned short* A0h = Xh + (size_t)(by * 128) * GK;
  const unsigned short* A0l = Xl + (size_t)(by * 128) * GK;
  const unsigned short* B0h = Bth + (size_t)(bx * 128) * GK;
  const unsigned short* B0l = Btl + (size_t)(bx * 128) * GK;

  const int rowBase = 32 * wave;
  const int srow = lane >> 2;
  const int skof = (lane & 3) * 8;

  floatx4 acc[4][4];
#pragma unroll
  for (int i = 0; i < 4; ++i)
#pragma unroll
    for (int j = 0; j < 4; ++j) acc[i][j] = (floatx4){0.f, 0.f, 0.f, 0.f};

  for (int k0 = 0; k0 < GK; k0 += 32) {
#pragma unroll
    for (int r = 0; r < 2; ++r) {
      int row = rowBase + 16 * r + srow;
      int ldsoff = (rowBase + 16 * r) * 32;
      __builtin_amdgcn_global_load_lds(
          (const __attribute__((address_space(1))) void*)(A0h + (size_t)row * GK + k0 + skof),
          (__attribute__((address_space(3))) void*)(sAh + ldsoff), 16, 0, 0);
      __builtin_amdgcn_global_load_lds(
          (const __attribute__((address_space(1))) void*)(A0l + (size_t)row * GK + k0 + skof),
          (__attribute__((address_space(3))) void*)(sAl + ldsoff), 16, 0, 0);
      __builtin_amdgcn_global_load_lds(
          (const __attribute__((address_space(1))) void*)(B0h + (size_t)row * GK + k0 + skof),
          (__attribute__((address_space(3))) void*)(sBh + ldsoff), 16, 0, 0);
      __builtin_amdgcn_global_load_lds(
          (const __attribute__((address_space(1))) void*)(B0l + (size_t)row * GK + k0 + skof),
          (__attribute__((address_space(3))) void*)(sBl + ldsoff), 16, 0, 0);
    }
    __syncthreads();

    short8 ah[4], al[4], bh[4], bl[4];
#pragma unroll
    for (int mi = 0; mi < 4; ++mi) {
      int off = (wr * 64 + mi * 16 + fm) * 32 + q * 8;
      ah[mi] = *(const short8*)(sAh + off);
      al[mi] = *(const short8*)(sAl + off);
    }
#pragma unroll
    for (int ni = 0; ni < 4; ++ni) {
      int off = (wc * 64 + ni * 16 + fm) * 32 + q * 8;
      bh[ni] = *(const short8*)(sBh + off);
      bl[ni] = *(const short8*)(sBl + off);
    }
#pragma unroll
    for (int mi = 0; mi < 4; ++mi)
#pragma unroll
      for (int ni = 0; ni < 4; ++ni) {
        acc[mi][ni] = __builtin_amdgcn_mfma_f32_16x16x32_bf16(ah[mi], bh[ni], acc[mi][ni], 0, 0, 0);
        acc[mi][ni] = __builtin_amdgcn_mfma_f32_16x16x32_bf16(al[mi], bh[ni], acc[mi][ni], 0, 0, 0);
        acc[mi][ni] = __builtin_amdgcn_mfma_f32_16x16x32_bf16(ah[mi], bl[ni], acc[mi][ni], 0, 0, 0);
      }
    __syncthreads();
  }

#pragma unroll
  for (int mi = 0; mi < 4; ++mi)
#pragma unroll
    for (int ni = 0; ni < 4; ++ni) {
      int col = bx * 128 + wc * 64 + ni * 16 + fm;
#pragma unroll
      for (int r = 0; r < 4; ++r) {
        int row = by * 128 + wr * 64 + mi * 16 + q * 4 + r;
        C[(size_t)row * 2048 + col] = acc[mi][ni][r];
      }
    }
}

// ---------------- row softmax in place (wave-shuffle reductions) ------------
__global__ __launch_bounds__(256) void softmax_kernel(float* __restrict__ C) {
  const int row = blockIdx.x;
  const int tid = threadIdx.x;
  const int lane = tid & 63;
  const int wv = tid >> 6;
  float4* p = (float4*)(C + (size_t)row * MCOLS);
  float4 a = p[tid];
  float4 b = p[tid + 256];

  __shared__ float wmax[4], wsum[4];

  float vmax = fmaxf(fmaxf(fmaxf(a.x, a.y), fmaxf(a.z, a.w)),
                     fmaxf(fmaxf(b.x, b.y), fmaxf(b.z, b.w)));
#pragma unroll
  for (int off = 32; off > 0; off >>= 1)
    vmax = fmaxf(vmax, __shfl_xor(vmax, off));
  if (lane == 0) wmax[wv] = vmax;
  __syncthreads();
  float m = fmaxf(fmaxf(wmax[0], wmax[1]), fmaxf(wmax[2], wmax[3]));

  float e[8];
  e[0] = __expf(a.x - m); e[1] = __expf(a.y - m); e[2] = __expf(a.z - m); e[3] = __expf(a.w - m);
  e[4] = __expf(b.x - m); e[5] = __expf(b.y - m); e[6] = __expf(b.z - m); e[7] = __expf(b.w - m);
  float sum = ((e[0] + e[1]) + (e[2] + e[3])) + ((e[4] + e[5]) + (e[6] + e[7]));
#pragma unroll
  for (int off = 32; off > 0; off >>= 1)
    sum += __shfl_xor(sum, off);
  if (lane == 0) wsum[wv] = sum;
  __syncthreads();
  float inv = 1.0f / (((wsum[0] + wsum[1]) + (wsum[2] + wsum[3])));

  a = make_float4(e[0] * inv, e[1] * inv, e[2] * inv, e[3] * inv);
  b = make_float4(e[4] * inv, e[5] * inv, e[6] * inv, e[7] * inv);
  p[tid] = a;
  p[tid + 256] = b;
}

// ---------------- launcher --------------------------------------------------
extern "C" void kernel_launch(void* const* d_in, const int* in_sizes, int n_in,
                              void* d_out, int out_size, void* d_ws, size_t ws_size,
                              hipStream_t stream) {
  const float* X      = (const float*)d_in[0];
  const float* weight = (const float*)d_in[1];
  const float* W1     = (const float*)d_in[2];
  const float* b1     = (const float*)d_in[3];
  const float* W2     = (const float*)d_in[4];
  const float* b2     = (const float*)d_in[5];
  const float* W3     = (const float*)d_in[6];
  const float* b3     = (const float*)d_in[7];
  float* out = (float*)d_out;

  const int N = 2048, M = 2048;
  const int Bdim = in_sizes[0] / N;   // 8192

  // workspace: rowS[2048] part[8*2048] (fp32) | Xh Xl [B*N] | Bth Btl [M*N] (ushort)
  float* rowS = (float*)d_ws;
  float* part = rowS + 2048;
  unsigned short* Xh  = (unsigned short*)(part + 8 * 2048);
  unsigned short* Xl  = Xh + (size_t)Bdim * N;
  unsigned short* Bth = Xl + (size_t)Bdim * N;
  unsigned short* Btl = Bth + (size_t)M * N;

  pre_kernel<<<CONV_BLOCKS + NROWS + 64, 256, 0, stream>>>(X, weight, Xh, Xl, part, rowS);

  nca_update_kernel<<<dim3(M / 32, N / 32), 256, 0, stream>>>(
      weight, part, rowS, W1, b1, W2, b2, W3, b3, Bth, Btl);

  gemm_kernel<<<dim3(M / 128, Bdim / 128), 256, 0, stream>>>(Xh, Xl, Bth, Btl, out);

  softmax_kernel<<<Bdim, 256, 0, stream>>>(out);
}